// Round 7
// baseline (118.927 us; speedup 1.0000x reference)
//
#include <hip/hip_runtime.h>

// pAUC loss — ROUND 12: DIAGNOSTIC (ablation-by-repetition, correctness kept)
//   bce(i,j) = -log(clip(sigmoid(pos_i - neg_j), 1e-6, 1-1e-6))
//   out = sum_i topk_j(bce, K=512) / (N_pos * N_neg)
// Structure = R10 (best known: GRID=256, two-phase compaction, level-2
// histogram select), but the ENTIRE select runs SELECT_REPS=6 times, each
// rep re-zeroing its state and recomputing the identical s_topk (barrier
// between a rep's scatter and the next rep's zeroing keeps it exact).
// Purpose: kernel_dur = base + 5*S surfaces the select's true marginal
// throughput cost S in the rocprof top-5 (cutoff ~39.4us = fill time);
// e2e gives S independently via (e2e - 70.1)/5. Six structural variants
// all landed 18.5-21.5us vs a ~6us work model; this buys attribution.
// Branches: S~15 -> select-once split next; S~3-6 -> residual is tail/
// launch -> stream-ordered multi-kernel next; S<3.7 -> tail elimination.

#define TOPK 512
#define BT   1024
#define GRID 256
#define EPT  16                  // BT * EPT = 16384 >= n_neg
#define NHIST 8                  // pass-0 histogram copies (wave pairs)
#define CAP   1024               // max candidates for fast path
#define POS_LDS 1024
#define SELECT_REPS 6            // DIAGNOSTIC: repeat select 6x
#define BCE_LO 1.0000005e-6f     // -log(1-1e-6)
#define BCE_HI 13.8155106f       // -log(1e-6)

__device__ __forceinline__ float decode_key(unsigned int ky) {
    unsigned int u = (ky >> 31) ? (ky ^ 0x80000000u) : (ky ^ 0xFFFFFFFFu);
    return __uint_as_float(u);
}

__global__ __launch_bounds__(BT, 4) void pauc_fused_kernel(
    const float* __restrict__ neg, int n_neg,
    const float* __restrict__ pos, int n_pos,
    float* __restrict__ out, float inv_denom, int k,
    float* __restrict__ partials, unsigned int* __restrict__ done) {
    const int tid  = threadIdx.x;
    const int lane = tid & 63;
    const int wv   = tid >> 6;

    __shared__ __align__(16) unsigned int hist[NHIST * 1024]; // 32 KB, pass-0
    __shared__ __align__(16) unsigned int hist2[1024];        // level-2 histogram
    __shared__ __align__(16) unsigned int cand2[1024 + 4];    // sub-bin cands (+pad)
    __shared__ float        s_topk[TOPK];
    __shared__ float        s_pos[POS_LDS];
    __shared__ unsigned int wtot[16];
    __shared__ unsigned int bc_digit, bc_kk, bc_cd;
    __shared__ unsigned int out_gt, out_cd2;
    __shared__ unsigned int sh_T, sh_g2;
    __shared__ float        s_red[BT / 64];

    const int rows_pb = (n_pos + GRID - 1) / GRID;      // 32 in harness
    const bool pos_in_lds = rows_pb <= POS_LDS;

    // -------- issue pos prefetch FIRST (latency hides under select) --------
    float pv0 = 0.0f;
    const int prow = blockIdx.x * rows_pb + tid;
    const bool pv0_v = pos_in_lds && (tid < rows_pb) && (prow < n_pos);
    if (pv0_v) pv0 = pos[prow];

    // ---------------- load all keys (every block, redundant) ----------------
    unsigned int keys[EPT];
    if (n_neg == BT * EPT) {                // harness case: float4 loads
        const float4* n4 = (const float4*)neg;
        #pragma unroll
        for (int t = 0; t < EPT / 4; ++t) {
            float4 v = n4[t * BT + tid];
            unsigned int u0 = __float_as_uint(v.x), u1 = __float_as_uint(v.y);
            unsigned int u2 = __float_as_uint(v.z), u3 = __float_as_uint(v.w);
            keys[4*t+0] = u0 ^ (0x80000000u | (unsigned)((int)u0 >> 31));
            keys[4*t+1] = u1 ^ (0x80000000u | (unsigned)((int)u1 >> 31));
            keys[4*t+2] = u2 ^ (0x80000000u | (unsigned)((int)u2 >> 31));
            keys[4*t+3] = u3 ^ (0x80000000u | (unsigned)((int)u3 >> 31));
        }
    } else {
        #pragma unroll
        for (int t = 0; t < EPT; ++t) {
            int i = t * BT + tid;
            unsigned int key = 0u;          // pad = smallest key
            if (i < n_neg) {
                unsigned int u = __float_as_uint(neg[i]);
                key = u ^ (0x80000000u | (unsigned)((int)u >> 31));
            }
            keys[t] = key;
        }
    }
    if (pos_in_lds && tid < rows_pb) s_pos[tid] = pv0_v ? pv0 : 0.0f;

    const unsigned int k0 = (unsigned)k;

    #pragma unroll 1
    for (int rep = 0; rep < SELECT_REPS; ++rep) {
    // zero histograms + counters (cand2 zeroed so pad slots are 0)
    #pragma unroll
    for (int i = 0; i < NHIST; ++i) hist[(i << 10) + tid] = 0u;
    hist2[tid] = 0u;
    cand2[tid] = 0u;
    if (tid < 4) cand2[1024 + tid] = 0u;
    if (tid == 0) { out_gt = 0u; out_cd2 = 0u; }
    __syncthreads();                                            // B1

    // ---------------- pass 0: privatized 10-bit histogram (copy/wave-pair) --
    {
        unsigned int* h = &hist[(unsigned)(wv >> 1) << 10];
        #pragma unroll
        for (int t = 0; t < EPT; ++t)
            atomicAdd(&h[keys[t] >> 22], 1u);
    }
    __syncthreads();                                            // B2

    // merge 8 copies (stride-1024: 2 lanes/bank -> free) + wave suffix scan
    unsigned int c = 0u;
    #pragma unroll
    for (int i = 0; i < NHIST; ++i) c += hist[(i << 10) + tid];
    unsigned int part = c;
    #pragma unroll
    for (int off = 1; off < 64; off <<= 1) {
        unsigned int v = __shfl_down(part, off, 64);
        if (lane + off < 64) part += v;
    }
    if (lane == 0) wtot[wv] = part;
    __syncthreads();                                            // B3
    // every wave redundantly suffix-scans the 16 wave totals (registers)
    unsigned int wsuf = 0u;
    #pragma unroll
    for (int w = 0; w < 16; ++w) wsuf += (w > wv) ? wtot[w] : 0u;
    unsigned int suf = part + wsuf;
    unsigned int s_next = __shfl_down(suf, 1, 64);
    if (lane == 63) s_next = wsuf;
    if (suf >= k0 && s_next < k0) {
        bc_digit = (unsigned)tid;
        bc_kk    = k0 - s_next;              // needed from chosen bin
        bc_cd    = c;                        // chosen bin's count
    }
    __syncthreads();                                            // B4

    const unsigned int B  = bc_digit;
    unsigned int kkv      = bc_kk;
    const unsigned int cd = bc_cd;

    if (cd <= CAP) {
        // ===== FAST PATH: two-phase scatter + fused level-2 histogram ======
        unsigned int gcnt = 0u;
        #pragma unroll
        for (int t = 0; t < EPT; ++t) {
            unsigned int ky  = keys[t];
            unsigned int bin = ky >> 22;
            unsigned long long m = __ballot(bin > B);
            gcnt += (unsigned)__popcll(m);
            if (bin == B)
                atomicAdd(&hist2[(ky >> 12) & 1023u], 1u);
        }
        unsigned int gbase = 0u;
        if (lane == 0) gbase = atomicAdd(&out_gt, gcnt);   // ONE atomic/wave
        gbase = __shfl(gbase, 0, 64);
        // sweep-1 phase B: scatter with running ballot-popcount base
        #pragma unroll
        for (int t = 0; t < EPT; ++t) {
            unsigned int ky = keys[t];
            bool g = (ky >> 22) > B;
            unsigned long long m = __ballot(g);
            if (g) {
                unsigned int idx = gbase +
                    (unsigned)__popcll(m & ((1ull << lane) - 1ull));
                s_topk[idx] = decode_key(ky);
            }
            gbase += (unsigned)__popcll(m);
        }
        __syncthreads();                                        // B5

        unsigned int Tkey  = 0u;
        unsigned int n_tie = 0u;
        const bool all_sel = (kkv == cd);    // whole bin selected
        if (!all_sel) {
            // ---- scan level-2 histogram (built during sweep-1) ----
            unsigned int c2 = hist2[tid];
            unsigned int p2 = c2;
            #pragma unroll
            for (int off = 1; off < 64; off <<= 1) {
                unsigned int v = __shfl_down(p2, off, 64);
                if (lane + off < 64) p2 += v;
            }
            if (lane == 0) wtot[wv] = p2;
            __syncthreads();                                    // B6
            unsigned int ws2 = 0u;
            #pragma unroll
            for (int w = 0; w < 16; ++w) ws2 += (w > wv) ? wtot[w] : 0u;
            unsigned int sf2 = p2 + ws2;
            unsigned int sn2 = __shfl_down(sf2, 1, 64);
            if (lane == 63) sn2 = ws2;
            if (sf2 >= kkv && sn2 < kkv) {
                bc_digit = (unsigned)tid;    // reuse (level-1 values consumed)
                bc_kk    = kkv - sn2;
                bc_cd    = c2;
            }
            __syncthreads();                                    // B7
            const unsigned int B2   = bc_digit;
            const unsigned int kkv2 = bc_kk;
            const unsigned int cd2  = bc_cd;
            const bool all2 = (kkv2 == cd2);
            if (!all2) {
                // compact sub-bin candidates from register keys
                #pragma unroll
                for (int t = 0; t < EPT; ++t) {
                    unsigned int ky = keys[t];
                    bool e2 = ((ky >> 22) == B) &&
                              (((ky >> 12) & 1023u) == B2);
                    unsigned long long m2 = __ballot(e2);
                    if (m2) {
                        unsigned int cnt = (unsigned)__popcll(m2);
                        unsigned int base;
                        if (lane == 0) base = atomicAdd(&out_cd2, cnt);
                        base = __shfl(base, 0, 64);
                        if (e2) {
                            unsigned int idx = base +
                                (unsigned)__popcll(m2 & ((1ull << lane) - 1ull));
                            cand2[idx] = ky;
                        }
                    }
                }
                __syncthreads();                                // B8
                // tiny rank-count over sub-bin candidates
                unsigned int y = (tid < (int)cd2) ? cand2[tid] : 0u;
                unsigned int gt = 0u, ge = 0u;
                const uint4* c4 = (const uint4*)cand2;
                const int nq = (int)((cd2 + 3u) >> 2);
                for (int j = 0; j < nq; ++j) {
                    uint4 q = c4[j];
                    gt += (unsigned)(q.x > y) + (unsigned)(q.y > y)
                        + (unsigned)(q.z > y) + (unsigned)(q.w > y);
                    ge += (unsigned)(q.x >= y) + (unsigned)(q.y >= y)
                        + (unsigned)(q.z >= y) + (unsigned)(q.w >= y);
                }
                if (tid < (int)cd2 && gt < kkv2 && ge >= kkv2) {
                    sh_T = y; sh_g2 = gt;
                }
                __syncthreads();                                // B9
                Tkey  = sh_T;
                n_tie = kkv2 - sh_g2;
            } else {
                Tkey  = ((B << 22) | (B2 << 12)) - 1u;
                n_tie = 0u;
            }
        }
        // final in-bin scatter, two-phase
        unsigned int scnt = 0u;
        #pragma unroll
        for (int t = 0; t < EPT; ++t) {
            unsigned int ky = keys[t];
            bool sel = ((ky >> 22) == B) && (all_sel || ky > Tkey);
            unsigned long long m = __ballot(sel);
            scnt += (unsigned)__popcll(m);
        }
        unsigned int sbase = 0u;
        if (lane == 0) sbase = atomicAdd(&out_gt, scnt);   // ONE atomic/wave
        sbase = __shfl(sbase, 0, 64);
        #pragma unroll
        for (int t = 0; t < EPT; ++t) {
            unsigned int ky = keys[t];
            bool sel = ((ky >> 22) == B) && (all_sel || ky > Tkey);
            unsigned long long m = __ballot(sel);
            if (sel) {
                unsigned int idx = sbase +
                    (unsigned)__popcll(m & ((1ull << lane) - 1ull));
                s_topk[idx] = decode_key(ky);
            }
            sbase += (unsigned)__popcll(m);
        }
        if ((unsigned)tid < n_tie)
            s_topk[k0 - n_tie + tid] = decode_key(Tkey);
    } else {
        // ============ FALLBACK: classic radix passes on low 22 bits ========
        unsigned int prefix = B << 22;
        unsigned int pmask  = 0xFFC00000u;
        const int      shifts2[3] = {12, 2, 0};
        const unsigned nbv2[3]    = {1024u, 1024u, 4u};
        for (int pass = 0; pass < 3; ++pass) {
            const int shift      = shifts2[pass];
            const unsigned nb    = nbv2[pass];
            const unsigned dmask = nb - 1u;
            if (tid < (int)nb) hist[tid] = 0u;
            __syncthreads();
            #pragma unroll
            for (int t = 0; t < EPT; ++t) {
                unsigned int ky = keys[t];
                if ((ky & pmask) == prefix)
                    atomicAdd(&hist[(ky >> shift) & dmask], 1u);
            }
            __syncthreads();
            unsigned int cc = (tid < (int)nb) ? hist[tid] : 0u;
            unsigned int p2 = cc;
            #pragma unroll
            for (int off = 1; off < 64; off <<= 1) {
                unsigned int v = __shfl_down(p2, off, 64);
                if (lane + off < 64) p2 += v;
            }
            if (lane == 0) wtot[wv] = p2;
            __syncthreads();
            unsigned int ws2 = 0u;
            #pragma unroll
            for (int w = 0; w < 16; ++w) ws2 += (w > wv) ? wtot[w] : 0u;
            unsigned int sf = p2 + ws2;
            unsigned int sn = __shfl_down(sf, 1, 64);
            if (lane == 63) sn = ws2;
            if (tid < (int)nb && sf >= kkv && sn < kkv) {
                bc_digit = (unsigned)tid;
                bc_kk    = kkv - sn;
                bc_cd    = cc;
            }
            __syncthreads();
            unsigned int newpref = prefix | (bc_digit << shift);
            if (pass < 2 && bc_kk == bc_cd && newpref != 0u) {
                prefix = newpref - 1u;       // whole bin: T below bin, no ties
                kkv = 0u;
                break;
            }
            prefix = newpref;
            kkv = bc_kk;
            pmask |= dmask << shift;
        }
        const unsigned int T = prefix;
        #pragma unroll
        for (int t = 0; t < EPT; ++t) {
            unsigned int ky = keys[t];
            bool g = ky > T;
            unsigned long long m = __ballot(g);
            if (m) {
                unsigned int cnt = (unsigned)__popcll(m);
                unsigned int base;
                if (lane == 0) base = atomicAdd(&out_gt, cnt);
                base = __shfl(base, 0, 64);
                if (g) {
                    unsigned int idx = base +
                        (unsigned)__popcll(m & ((1ull << lane) - 1ull));
                    s_topk[idx] = decode_key(ky);
                }
            }
        }
        if ((unsigned)tid < kkv)
            s_topk[(k0 - kkv) + tid] = decode_key(T);
    }
    __syncthreads();                                            // B10 (per rep)
    }   // end SELECT_REPS diagnostic loop

    // -------- bce partial sum: 1 col/thread, 2 row-groups from LDS ----------
    const int col = tid & (TOPK - 1);
    const int rg  = tid >> 9;                          // 0 or 1
    const bool cv = col < k;
    const float tv = cv ? s_topk[col] : 0.0f;
    const int rpg  = (rows_pb + (BT / TOPK) - 1) / (BT / TOPK);  // 16
    const int rbase = blockIdx.x * rows_pb + rg * rpg;
    int lim = n_pos - rbase;
    int lmax = rows_pb - rg * rpg;
    if (lim > lmax) lim = lmax;
    if (lim > rpg)  lim = rpg;
    if (lim < 0)    lim = 0;
    float acc = 0.0f;
    if (pos_in_lds) {
        const float* sp = &s_pos[rg * rpg];
        #pragma unroll 4
        for (int r = 0; r < lim; ++r) {
            float pv = sp[r];
            // -log(clip(sigmoid(pv - tv))) = clamp(log(1 + exp(tv - pv)))
            float b = __logf(1.0f + __expf(tv - pv));
            b = fminf(fmaxf(b, BCE_LO), BCE_HI);
            acc += b;
        }
    } else {
        for (int r = 0; r < lim; ++r) {
            float pv = pos[rbase + r];
            float b = __logf(1.0f + __expf(tv - pv));
            b = fminf(fmaxf(b, BCE_LO), BCE_HI);
            acc += b;
        }
    }
    if (!cv) acc = 0.0f;
    #pragma unroll
    for (int off = 32; off > 0; off >>= 1) acc += __shfl_down(acc, off, 64);
    if (lane == 0) s_red[wv] = acc;
    __syncthreads();                                            // B11
    if (tid == 0) {
        float t = 0.0f;
        #pragma unroll
        for (int w = 0; w < BT / 64; ++w) t += s_red[w];
        __hip_atomic_store(&partials[blockIdx.x], t,
                           __ATOMIC_RELAXED, __HIP_MEMORY_SCOPE_AGENT);
        __hip_atomic_store(&done[blockIdx.x], 1u,
                           __ATOMIC_RELEASE, __HIP_MEMORY_SCOPE_AGENT);
    }

    // ---------------- block 0: gather the 256 partials ----------------------
    if (blockIdx.x == 0) {
        float a = 0.0f;
        if (tid < GRID) {
            while (__hip_atomic_load(&done[tid], __ATOMIC_RELAXED,
                                     __HIP_MEMORY_SCOPE_AGENT) != 1u)
                __builtin_amdgcn_s_sleep(1);
            __builtin_amdgcn_fence(__ATOMIC_ACQUIRE, "agent");
            a = __hip_atomic_load(&partials[tid], __ATOMIC_RELAXED,
                                  __HIP_MEMORY_SCOPE_AGENT);
        }
        #pragma unroll
        for (int off = 32; off > 0; off >>= 1) a += __shfl_down(a, off, 64);
        if (lane == 0) s_red[wv] = a;
        __syncthreads();
        if (tid == 0) {
            float t = 0.0f;
            #pragma unroll
            for (int w = 0; w < BT / 64; ++w) t += s_red[w];
            out[0] = t * inv_denom;
        }
    }
}

extern "C" void kernel_launch(void* const* d_in, const int* in_sizes, int n_in,
                              void* d_out, int out_size, void* d_ws, size_t ws_size,
                              hipStream_t stream) {
    const float* neg = (const float*)d_in[0];   // score_neg, 16384
    const float* pos = (const float*)d_in[1];   // score_pos, 8192
    const int n_neg = in_sizes[0];
    const int n_pos = in_sizes[1];
    float* out = (float*)d_out;
    float* ws  = (float*)d_ws;

    int k = TOPK; if (k > n_neg) k = n_neg;
    float*        partials = ws;                             // [0, GRID)
    unsigned int* done     = (unsigned int*)(ws + GRID);     // [GRID, 2*GRID)

    const float inv_denom = (float)(1.0 / ((double)n_pos * (double)n_neg));
    pauc_fused_kernel<<<GRID, BT, 0, stream>>>(
        neg, n_neg, pos, n_pos, out, inv_denom, k, partials, done);
}

// Round 8
// 67.107 us; speedup vs baseline: 1.7722x; 1.7722x over previous
//
#include <hip/hip_runtime.h>

// pAUC loss, single-dispatch, REDUNDANT-SELECT, round 13 (T-only select):
//   bce(i,j) = -log(clip(sigmoid(pos_i - neg_j), 1e-6, 1-1e-6))
//   out = sum_i topk_j(bce, K=512) / (N_pos * N_neg)
// bce monotone in neg_j => row top-K = K largest negatives.
//
// R12 diagnostic (6x select repetition): S = 9.8us/select, base = 11us
// (ramp + cold load + BCE + gather). VALU 2.8us/S, LDS-conflict 0.9us/S,
// ~5.5us latency. Split kernels can't help (redundant select is wall-
// parallel); R6 showed 2 blocks/CU serializes ~40% of S. So R13 cuts S's
// work terms, minimally disturbing verified machinery:
//  - T-ONLY SELECT: BCE needs only (T, n_tie), not a materialized s_topk.
//    Deleted: sweep-1 ballot counting + bins>B scatter, final two-phase
//    scatter, tie-fill, s_topk (~2 sweeps of VALU/LDS + 2 barriers).
//  - WAVE-LOCAL BCE: each wave compacts ITS OWN selected keys (key > T)
//    into a wave-private LDS buf (ballot+mbcnt, no atomics/barriers),
//    then balanced BCE striped over lanes. Ties added analytically:
//    n_tie * bce(decode(T), row) by threads tid < rows_pb.
//  - level-2 histogram built from register keys (only surviving sweep);
//    fallback (cd2 > CAP, massive ties) = 2 radix passes on bits 11..0
//    from the 20-bit prefix (same verified skeleton).
// NOTE: BCE summation order changed -> absmax becomes ~1e-9 (was 0.0).

#define TOPK 512
#define BT   1024
#define GRID 256
#define EPT  16                  // BT * EPT = 16384 >= n_neg
#define NHIST 8                  // pass-0 histogram copies (wave pairs)
#define CAP   1024               // max sub-bin candidates for rank path
#define POS_LDS 1024
#define BCE_LO 1.0000005e-6f     // -log(1-1e-6)
#define BCE_HI 13.8155106f       // -log(1e-6)

__device__ __forceinline__ float decode_key(unsigned int ky) {
    unsigned int u = (ky >> 31) ? (ky ^ 0x80000000u) : (ky ^ 0xFFFFFFFFu);
    return __uint_as_float(u);
}

__global__ __launch_bounds__(BT, 4) void pauc_fused_kernel(
    const float* __restrict__ neg, int n_neg,
    const float* __restrict__ pos, int n_pos,
    float* __restrict__ out, float inv_denom, int k,
    float* __restrict__ partials, unsigned int* __restrict__ done) {
    const int tid  = threadIdx.x;
    const int lane = tid & 63;
    const int wv   = tid >> 6;

    // hist: pass-0 copies (32 KB); dead after scan1/fallback -> reused as
    // 16 wave-private compaction buffers of 512 floats each.
    __shared__ __align__(16) unsigned int hist[NHIST * 1024];
    __shared__ __align__(16) unsigned int hist2[1024];        // level-2 bins
    __shared__ __align__(16) unsigned int cand2[CAP + 4];     // sub-bin cands
    __shared__ float        s_pos[POS_LDS];
    __shared__ unsigned int wtot[16];
    __shared__ unsigned int bc_digit, bc_kk, bc_cd;
    __shared__ unsigned int out_cd2;
    __shared__ unsigned int sh_T, sh_g2;
    __shared__ float        s_red[BT / 64];

    const int rows_pb = (n_pos + GRID - 1) / GRID;      // 32 in harness
    const bool pos_in_lds = rows_pb <= POS_LDS;

    // -------- issue pos prefetch FIRST (latency hides under select) --------
    float pv0 = 0.0f;
    const int prow = blockIdx.x * rows_pb + tid;
    const bool pv0_v = pos_in_lds && (tid < rows_pb) && (prow < n_pos);
    if (pv0_v) pv0 = pos[prow];

    // ---------------- load all keys (every block, redundant) ----------------
    unsigned int keys[EPT];
    if (n_neg == BT * EPT) {                // harness case: float4 loads
        const float4* n4 = (const float4*)neg;
        #pragma unroll
        for (int t = 0; t < EPT / 4; ++t) {
            float4 v = n4[t * BT + tid];
            unsigned int u0 = __float_as_uint(v.x), u1 = __float_as_uint(v.y);
            unsigned int u2 = __float_as_uint(v.z), u3 = __float_as_uint(v.w);
            keys[4*t+0] = u0 ^ (0x80000000u | (unsigned)((int)u0 >> 31));
            keys[4*t+1] = u1 ^ (0x80000000u | (unsigned)((int)u1 >> 31));
            keys[4*t+2] = u2 ^ (0x80000000u | (unsigned)((int)u2 >> 31));
            keys[4*t+3] = u3 ^ (0x80000000u | (unsigned)((int)u3 >> 31));
        }
    } else {
        #pragma unroll
        for (int t = 0; t < EPT; ++t) {
            int i = t * BT + tid;
            unsigned int key = 0u;          // pad = smallest key
            if (i < n_neg) {
                unsigned int u = __float_as_uint(neg[i]);
                key = u ^ (0x80000000u | (unsigned)((int)u >> 31));
            }
            keys[t] = key;
        }
    }

    // zero histograms + counters (cand2 zeroed so rank pads read 0)
    #pragma unroll
    for (int i = 0; i < NHIST; ++i) hist[(i << 10) + tid] = 0u;
    hist2[tid] = 0u;
    cand2[tid] = 0u;
    if (tid < 4) cand2[CAP + tid] = 0u;
    if (tid == 0) out_cd2 = 0u;
    if (pos_in_lds && tid < rows_pb) s_pos[tid] = pv0_v ? pv0 : 0.0f;
    __syncthreads();                                            // B1

    // ---------------- pass 0: privatized 10-bit histogram (copy/wave-pair) --
    {
        unsigned int* h = &hist[(unsigned)(wv >> 1) << 10];
        #pragma unroll
        for (int t = 0; t < EPT; ++t)
            atomicAdd(&h[keys[t] >> 22], 1u);
    }
    __syncthreads();                                            // B2

    // merge 8 copies (stride-1024: conflict-free) + wave suffix scan
    unsigned int c = 0u;
    #pragma unroll
    for (int i = 0; i < NHIST; ++i) c += hist[(i << 10) + tid];
    unsigned int part = c;
    #pragma unroll
    for (int off = 1; off < 64; off <<= 1) {
        unsigned int v = __shfl_down(part, off, 64);
        if (lane + off < 64) part += v;
    }
    if (lane == 0) wtot[wv] = part;
    __syncthreads();                                            // B3
    // every wave redundantly suffix-scans the 16 wave totals (registers)
    unsigned int wsuf = 0u;
    #pragma unroll
    for (int w = 0; w < 16; ++w) wsuf += (w > wv) ? wtot[w] : 0u;
    const unsigned int k0 = (unsigned)k;
    unsigned int suf = part + wsuf;
    unsigned int s_next = __shfl_down(suf, 1, 64);
    if (lane == 63) s_next = wsuf;
    if (suf >= k0 && s_next < k0) {
        bc_digit = (unsigned)tid;
        bc_kk    = k0 - s_next;              // needed from chosen bin
        bc_cd    = c;                        // chosen bin's count
    }
    __syncthreads();                                            // B4

    const unsigned int B  = bc_digit;
    const unsigned int kkv = bc_kk;
    const unsigned int cd  = bc_cd;

    unsigned int Tkey  = 0u;
    unsigned int n_tie = 0u;
    if (kkv == cd) {
        // whole level-1 bin selected: T = bin lower boundary - 1, no ties.
        // (B==0 with kkv==cd impossible for k < total-counted keys.)
        Tkey = B ? ((B << 22) - 1u) : 0u;
    } else {
        // ---- level-2 histogram (bits 12..21) over bin==B keys (registers) --
        #pragma unroll
        for (int t = 0; t < EPT; ++t) {
            unsigned int ky = keys[t];
            if ((ky >> 22) == B)
                atomicAdd(&hist2[(ky >> 12) & 1023u], 1u);
        }
        __syncthreads();                                        // B5
        unsigned int c2 = hist2[tid];
        unsigned int p2 = c2;
        #pragma unroll
        for (int off = 1; off < 64; off <<= 1) {
            unsigned int v = __shfl_down(p2, off, 64);
            if (lane + off < 64) p2 += v;
        }
        if (lane == 0) wtot[wv] = p2;
        __syncthreads();                                        // B6
        unsigned int ws2 = 0u;
        #pragma unroll
        for (int w = 0; w < 16; ++w) ws2 += (w > wv) ? wtot[w] : 0u;
        unsigned int sf2 = p2 + ws2;
        unsigned int sn2 = __shfl_down(sf2, 1, 64);
        if (lane == 63) sn2 = ws2;
        if (sf2 >= kkv && sn2 < kkv) {
            bc_digit = (unsigned)tid;        // reuse (level-1 values consumed)
            bc_kk    = kkv - sn2;
            bc_cd    = c2;
        }
        __syncthreads();                                        // B7
        const unsigned int B2   = bc_digit;
        const unsigned int kkv2 = bc_kk;
        const unsigned int cd2  = bc_cd;
        if (kkv2 == cd2) {
            // whole sub-bin selected: T just below sub-bin, no ties.
            // (B,B2)==(0,0) here would imply kkv==cd, handled above.
            Tkey = ((B << 22) | (B2 << 12)) - 1u;
        } else if (cd2 <= CAP) {
            // compact sub-bin candidates from register keys (expected 1-3)
            #pragma unroll
            for (int t = 0; t < EPT; ++t) {
                unsigned int ky = keys[t];
                bool e2 = ((ky >> 22) == B) && (((ky >> 12) & 1023u) == B2);
                unsigned long long m2 = __ballot(e2);
                if (m2) {
                    unsigned int cnt = (unsigned)__popcll(m2);
                    unsigned int base;
                    if (lane == 0) base = atomicAdd(&out_cd2, cnt);
                    base = __shfl(base, 0, 64);
                    if (e2) {
                        unsigned int idx = base +
                            (unsigned)__popcll(m2 & ((1ull << lane) - 1ull));
                        cand2[idx] = ky;
                    }
                }
            }
            __syncthreads();                                    // B8
            // tiny rank-count: gt=#cand2>y, ge=#cand2>=y (uint4 broadcast;
            // zero pads never raise gt; participants have y>0)
            if (tid < (int)cd2) {
                unsigned int y = cand2[tid];
                unsigned int gt = 0u, ge = 0u;
                const uint4* c4 = (const uint4*)cand2;
                const int nq = (int)((cd2 + 3u) >> 2);
                for (int j = 0; j < nq; ++j) {
                    uint4 q = c4[j];
                    gt += (unsigned)(q.x > y) + (unsigned)(q.y > y)
                        + (unsigned)(q.z > y) + (unsigned)(q.w > y);
                    ge += (unsigned)(q.x >= y) + (unsigned)(q.y >= y)
                        + (unsigned)(q.z >= y) + (unsigned)(q.w >= y);
                }
                if (gt < kkv2 && ge >= kkv2) { sh_T = y; sh_g2 = gt; }
            }
            __syncthreads();                                    // B9
            Tkey  = sh_T;
            n_tie = kkv2 - sh_g2;
        } else {
            // ===== FALLBACK (massive ties): radix passes on bits 11..0 =====
            unsigned int prefix = (B << 22) | (B2 << 12);
            unsigned int pmask  = 0xFFFFF000u;
            unsigned int kkvf   = kkv2;
            const int      shifts2[2] = {2, 0};
            const unsigned nbv2[2]    = {1024u, 4u};
            for (int pass = 0; pass < 2; ++pass) {
                const int shift      = shifts2[pass];
                const unsigned nb    = nbv2[pass];
                const unsigned dmask = nb - 1u;
                if (tid < (int)nb) hist[tid] = 0u;
                __syncthreads();
                #pragma unroll
                for (int t = 0; t < EPT; ++t) {
                    unsigned int ky = keys[t];
                    if ((ky & pmask) == prefix)
                        atomicAdd(&hist[(ky >> shift) & dmask], 1u);
                }
                __syncthreads();
                unsigned int cc = (tid < (int)nb) ? hist[tid] : 0u;
                unsigned int pf = cc;
                #pragma unroll
                for (int off = 1; off < 64; off <<= 1) {
                    unsigned int v = __shfl_down(pf, off, 64);
                    if (lane + off < 64) pf += v;
                }
                if (lane == 0) wtot[wv] = pf;
                __syncthreads();
                unsigned int wsf = 0u;
                #pragma unroll
                for (int w = 0; w < 16; ++w) wsf += (w > wv) ? wtot[w] : 0u;
                unsigned int sff = pf + wsf;
                unsigned int snf = __shfl_down(sff, 1, 64);
                if (lane == 63) snf = wsf;
                if (tid < (int)nb && sff >= kkvf && snf < kkvf) {
                    bc_digit = (unsigned)tid;
                    bc_kk    = kkvf - snf;
                    bc_cd    = cc;
                }
                __syncthreads();
                unsigned int newpref = prefix | (bc_digit << shift);
                if (pass < 1 && bc_kk == bc_cd && newpref != 0u) {
                    prefix = newpref - 1u;   // whole bin: T below bin, no ties
                    kkvf = 0u;
                    break;
                }
                prefix = newpref;
                kkvf = bc_kk;
                pmask |= dmask << shift;
            }
            Tkey  = prefix;
            n_tie = kkvf;
        }
    }

    // ---- wave-local compaction of selected keys (no atomics, no barrier) ---
    // hist is dead (pass-0 / fallback both consumed behind barriers).
    float* wbuf = (float*)&hist[(unsigned)wv << 9];      // 512 slots per wave
    unsigned int cnt = 0u;
    #pragma unroll
    for (int t = 0; t < EPT; ++t) {
        unsigned int ky = keys[t];
        bool s = ky > Tkey;
        unsigned long long m = __ballot(s);
        if (s) {
            unsigned int idx = cnt +
                (unsigned)__popcll(m & ((1ull << lane) - 1ull));
            wbuf[idx] = decode_key(ky);
        }
        cnt += (unsigned)__popcll(m);
    }

    // -------- bce partial sum: this wave's selected cols x block's rows -----
    const int rpg   = (rows_pb + 1) >> 1;
    const int rbase = blockIdx.x * rows_pb;
    int lim0 = rows_pb - 0 * rpg;  if (lim0 > rpg) lim0 = rpg;
    int lim1 = rows_pb - rpg;      if (lim1 > rpg) lim1 = rpg;
    {   // clip to n_pos
        int a0 = n_pos - rbase;           if (a0 < 0) a0 = 0;
        int a1 = n_pos - rbase - rpg;     if (a1 < 0) a1 = 0;
        if (lim0 > a0) lim0 = a0;
        if (lim1 > a1) lim1 = a1;
        if (lim1 < 0)  lim1 = 0;
    }
    float acc = 0.0f;
    const unsigned int total = cnt << 1;            // (col, row-half) pairs
    if (pos_in_lds) {
        for (unsigned int j = lane; j < total; j += 64) {
            float tv = wbuf[j >> 1];
            int h = (int)(j & 1u);
            const float* sp = &s_pos[h * rpg];
            int lim = h ? lim1 : lim0;
            for (int r = 0; r < lim; ++r) {
                float b = __logf(1.0f + __expf(tv - sp[r]));
                b = fminf(fmaxf(b, BCE_LO), BCE_HI);
                acc += b;
            }
        }
    } else {
        for (unsigned int j = lane; j < total; j += 64) {
            float tv = wbuf[j >> 1];
            int h = (int)(j & 1u);
            const float* gp = &pos[rbase + h * rpg];
            int lim = h ? lim1 : lim0;
            for (int r = 0; r < lim; ++r) {
                float b = __logf(1.0f + __expf(tv - gp[r]));
                b = fminf(fmaxf(b, BCE_LO), BCE_HI);
                acc += b;
            }
        }
    }
    // tie term: n_tie copies of decode(Tkey) against each row
    if (n_tie && tid < rows_pb && (rbase + tid) < n_pos) {
        float tvT = decode_key(Tkey);
        float pv  = pos_in_lds ? s_pos[tid] : pos[rbase + tid];
        float b = __logf(1.0f + __expf(tvT - pv));
        b = fminf(fmaxf(b, BCE_LO), BCE_HI);
        acc += (float)n_tie * b;
    }
    #pragma unroll
    for (int off = 32; off > 0; off >>= 1) acc += __shfl_down(acc, off, 64);
    if (lane == 0) s_red[wv] = acc;
    __syncthreads();                                            // B10
    if (tid == 0) {
        float t = 0.0f;
        #pragma unroll
        for (int w = 0; w < BT / 64; ++w) t += s_red[w];
        __hip_atomic_store(&partials[blockIdx.x], t,
                           __ATOMIC_RELAXED, __HIP_MEMORY_SCOPE_AGENT);
        __hip_atomic_store(&done[blockIdx.x], 1u,
                           __ATOMIC_RELEASE, __HIP_MEMORY_SCOPE_AGENT);
    }

    // ---------------- block 0: gather the 256 partials ----------------------
    if (blockIdx.x == 0) {
        float a = 0.0f;
        if (tid < GRID) {
            while (__hip_atomic_load(&done[tid], __ATOMIC_RELAXED,
                                     __HIP_MEMORY_SCOPE_AGENT) != 1u)
                __builtin_amdgcn_s_sleep(1);
            __builtin_amdgcn_fence(__ATOMIC_ACQUIRE, "agent");
            a = __hip_atomic_load(&partials[tid], __ATOMIC_RELAXED,
                                  __HIP_MEMORY_SCOPE_AGENT);
        }
        #pragma unroll
        for (int off = 32; off > 0; off >>= 1) a += __shfl_down(a, off, 64);
        if (lane == 0) s_red[wv] = a;
        __syncthreads();
        if (tid == 0) {
            float t = 0.0f;
            #pragma unroll
            for (int w = 0; w < BT / 64; ++w) t += s_red[w];
            out[0] = t * inv_denom;
        }
    }
}

extern "C" void kernel_launch(void* const* d_in, const int* in_sizes, int n_in,
                              void* d_out, int out_size, void* d_ws, size_t ws_size,
                              hipStream_t stream) {
    const float* neg = (const float*)d_in[0];   // score_neg, 16384
    const float* pos = (const float*)d_in[1];   // score_pos, 8192
    const int n_neg = in_sizes[0];
    const int n_pos = in_sizes[1];
    float* out = (float*)d_out;
    float* ws  = (float*)d_ws;

    int k = TOPK; if (k > n_neg) k = n_neg;
    float*        partials = ws;                             // [0, GRID)
    unsigned int* done     = (unsigned int*)(ws + GRID);     // [GRID, 2*GRID)

    const float inv_denom = (float)(1.0 / ((double)n_pos * (double)n_neg));
    pauc_fused_kernel<<<GRID, BT, 0, stream>>>(
        neg, n_neg, pos, n_pos, out, inv_denom, k, partials, done);
}